// Round 1
// 1836.456 us; speedup vs baseline: 1.0187x; 1.0187x over previous
//
#include <hip/hip_runtime.h>

// (B,C,H,W) = (4,96,128,256), level-6 decoder.
constexpr int Bn = 4, Hh = 128, Ww = 256, HWn = Hh * Ww;   // 32768
constexpr int FC = 433;
constexpr int FLOW_ELEMS = Bn * 2 * HWn;                    // 262144
// bf16 channel-minor shadow feat: [B][Hp][Wp][Cp], halos + channel pad zeroed
constexpr int Hp = 130, Wp = 258, Cp = 448;
constexpr size_t FB_BATCH = (size_t)Hp * Wp * Cp;           // 15,025,920
constexpr size_t FEATBF_ELEMS = (size_t)Bn * FB_BATCH;      // 60,103,680 (x2B = 120.2 MB)

using short8 = __attribute__((ext_vector_type(8))) short;   // 8 x bf16 (4 VGPRs)
using f32x4  = __attribute__((ext_vector_type(4))) float;

__device__ __forceinline__ unsigned short f2bf(float v) {
    union { float f; unsigned u; } x; x.f = v;
    unsigned r = x.u + 0x7fff + ((x.u >> 16) & 1);          // RNE
    return (unsigned short)(r >> 16);
}

// ---------------------------------------------------------------------------
// Weight pretransform: OIHW fp32 [CO][CI][3][3] -> bf16 [9][COP][CIP], zero-pad.
// ---------------------------------------------------------------------------
__global__ void wtrans(const float* __restrict__ src, unsigned short* __restrict__ dst,
                       int CO, int CI, int COP, int CIP)
{
    int idx = blockIdx.x * 256 + threadIdx.x;
    int total = 9 * COP * CIP;
    if (idx >= total) return;
    int t  = idx / (COP * CIP);
    int r  = idx % (COP * CIP);
    int co = r / CIP;
    int ci = r % CIP;
    float v = (co < CO && ci < CI) ? src[((size_t)co * CI + ci) * 9 + t] : 0.f;
    dst[idx] = f2bf(v);
}

// ---------------------------------------------------------------------------
// Correlation (fp32, LDS-staged) + lrelu; writes fp32 feat ch[352,433) and the
// bf16 shadow (packed ushort4 stores, channel-minor).
//
// Block = one (b, y) row, 256 threads = 256 pixels. Per 6-channel chunk the
// 9 B-rows (y-4..y+4, 264 cols w/ x-halo) are staged to LDS with coalesced
// dword loads; the 81-tap loop is then ds_read_b32 (stride-1, conflict-free,
// compile-time offsets) + v_fmac_f32 instead of 7776 latency-bound global
// loads per thread. x-halo cols (xx<0 / xx>=256) are ALWAYS out of image ->
// zeroed once before the chunk loop.
// ---------------------------------------------------------------------------
__global__ __launch_bounds__(256) void corr_kernel(
    const float* __restrict__ A, const float* __restrict__ B2,
    float* __restrict__ feat, unsigned short* __restrict__ fbf)
{
    constexpr int NC = 6;                        // channels staged per chunk
    __shared__ float sB[NC][9][264];             // 57,024 B (2 blocks/CU fit)

    const int x = threadIdx.x, y = blockIdx.x, b = blockIdx.y;

    // zero the x-halo columns once (cols 0..3 and 260..263 never change)
    if (x < 8) {
        const int col = (x < 4) ? x : (256 + x);
#pragma unroll
        for (int cl = 0; cl < NC; ++cl)
#pragma unroll
            for (int row = 0; row < 9; ++row)
                sB[cl][row][col] = 0.f;
    }

    float acc[81];
#pragma unroll
    for (int d = 0; d < 81; ++d) acc[d] = 0.f;

    const size_t cb = (size_t)b * 96;
    const float* ap = A  + cb * HWn + y * Ww + x;
    const float* bp = B2 + cb * HWn + x;

    for (int c0 = 0; c0 < 96; c0 += NC) {
        __syncthreads();                          // prev compute done / halo done
        // stage: 9 rows x NC channels, one coalesced dword load per (cl,row)
#pragma unroll
        for (int cl = 0; cl < NC; ++cl) {
            const float* src = bp + (size_t)(c0 + cl) * HWn;
#pragma unroll
            for (int row = 0; row < 9; ++row) {
                const int yy = y + row - 4;       // wave-uniform predicate
                const float v = ((unsigned)yy < 128u) ? src[yy * Ww] : 0.f;
                sB[cl][row][4 + x] = v;
            }
        }
        float av[NC];
#pragma unroll
        for (int cl = 0; cl < NC; ++cl) av[cl] = ap[(size_t)(c0 + cl) * HWn];
        __syncthreads();
#pragma unroll
        for (int cl = 0; cl < NC; ++cl)
#pragma unroll
            for (int dy = 0; dy < 9; ++dy)
#pragma unroll
                for (int dx = 0; dx < 9; ++dx)
                    acc[dy * 9 + dx] = fmaf(av[cl], sB[cl][dy][x + dx], acc[dy * 9 + dx]);
    }

    float* op = feat + ((size_t)b * FC + 352) * HWn + y * Ww + x;
    unsigned short bv16[81];
#pragma unroll
    for (int d = 0; d < 81; ++d) {
        float v = acc[d];
        v = (v >= 0.f) ? v : 0.1f * v;
        op[(size_t)d * HWn] = v;
        bv16[d] = f2bf(v);
    }
    unsigned short* bq = fbf + ((size_t)(b * Hp + y + 1) * Wp + (x + 1)) * Cp + 352;
#pragma unroll
    for (int k = 0; k < 20; ++k) {
        ushort4 p; p.x = bv16[4*k]; p.y = bv16[4*k+1]; p.z = bv16[4*k+2]; p.w = bv16[4*k+3];
        *(ushort4*)(bq + 4 * k) = p;
    }
    bq[80] = bv16[80];
}

// ---------------------------------------------------------------------------
// MFMA implicit-GEMM 3x3 conv. M=co (weights=A operand), N=pixels (input=B),
// K=ci. Wave = 64 px x (NT*16) co. Reads channel suffix [CS,448) of the bf16
// shadow; CS = 448-CIP. A-frag: lane(co=l&15, ci=quad*8+j) -> 16B from
// Wt[t][co][ci]. B-frag: lane(px=l&15, ci=quad*8+j) -> 16B from shadow.
// D: col(pixel)=l&15, row(co)=quad*4+r  [guide §3, m89/m120 verified].
// FUSE: flow head epilogue (bias + vx/vy weighted mean), no feat write.
// ---------------------------------------------------------------------------
template<int CIP, int NT, bool FUSE>
__global__ __launch_bounds__(256) void conv_mfma(
    const unsigned short* __restrict__ fbf,
    const unsigned short* __restrict__ Wt,     // [9][NT*16][CIP] bf16
    const float* __restrict__ bias,
    float* __restrict__ fout,                  // convs: feat + co_start*HW; flow: flow base
    unsigned short* __restrict__ bfout, int co_start)
{
    constexpr int CS = 448 - CIP;
    const int tid  = threadIdx.x;
    const int lane = tid & 63;
    const int wv   = tid >> 6;
    const int n16  = lane & 15;
    const int quad = lane >> 4;
    const int y = blockIdx.x, b = blockIdx.y;
    const int x0 = wv * 64;

    f32x4 acc[NT][4];
#pragma unroll
    for (int mt = 0; mt < NT; ++mt)
#pragma unroll
        for (int nt = 0; nt < 4; ++nt)
#pragma unroll
            for (int r = 0; r < 4; ++r) acc[mt][nt][r] = 0.f;

    if (!FUSE) {
#pragma unroll
        for (int mt = 0; mt < NT; ++mt) {
            f32x4 bv = *(const f32x4*)(bias + mt * 16 + quad * 4);
#pragma unroll
            for (int nt = 0; nt < 4; ++nt) acc[mt][nt] = bv;
        }
    }

    const unsigned short* fb = fbf + (size_t)b * FB_BATCH;
    const int xb = x0 + n16 + 1;   // padded-x for dx=0

#pragma unroll 1
    for (int ci0 = 0; ci0 < CIP; ci0 += 32) {
#pragma unroll
        for (int tap = 0; tap < 9; ++tap) {
            const int dy = tap / 3 - 1, dx = tap % 3 - 1;
            const unsigned short* bp =
                fb + ((size_t)(y + 1 + dy) * Wp + (xb + dx)) * Cp + (CS + ci0 + quad * 8);
            short8 Bf[4];
#pragma unroll
            for (int nt = 0; nt < 4; ++nt)
                Bf[nt] = *(const short8*)(bp + (size_t)nt * 16 * Cp);

            const unsigned short* apw =
                Wt + ((size_t)tap * (NT * 16) + n16) * CIP + (ci0 + quad * 8);
#pragma unroll
            for (int mt = 0; mt < NT; ++mt) {
                short8 Af = *(const short8*)(apw + (size_t)mt * 16 * CIP);
#pragma unroll
                for (int nt = 0; nt < 4; ++nt)
                    acc[mt][nt] = __builtin_amdgcn_mfma_f32_16x16x32_bf16(
                        Af, Bf[nt], acc[mt][nt], 0, 0, 0);
            }
        }
    }

    if (!FUSE) {
#pragma unroll
        for (int mt = 0; mt < NT; ++mt)
#pragma unroll
            for (int nt = 0; nt < 4; ++nt) {
                const int px = x0 + nt * 16 + n16;
                float* op = fout + ((size_t)b * FC + mt * 16 + quad * 4) * HWn + y * Ww + px;
                unsigned short* bq = bfout +
                    ((size_t)(b * Hp + y + 1) * Wp + (px + 1)) * Cp + co_start + mt * 16 + quad * 4;
                ushort4 pk;
                float v0 = acc[mt][nt][0]; v0 = v0 >= 0.f ? v0 : 0.1f * v0; op[0]       = v0; pk.x = f2bf(v0);
                float v1 = acc[mt][nt][1]; v1 = v1 >= 0.f ? v1 : 0.1f * v1; op[HWn]     = v1; pk.y = f2bf(v1);
                float v2 = acc[mt][nt][2]; v2 = v2 >= 0.f ? v2 : 0.1f * v2; op[2 * HWn] = v2; pk.z = f2bf(v2);
                float v3 = acc[mt][nt][3]; v3 = v3 >= 0.f ? v3 : 0.1f * v3; op[3 * HWn] = v3; pk.w = f2bf(v3);
                *(ushort4*)bq = pk;
            }
    } else {
#pragma unroll
        for (int nt = 0; nt < 4; ++nt) {
            float fx = 0.f, fy = 0.f;
#pragma unroll
            for (int mt = 0; mt < NT; ++mt)
#pragma unroll
                for (int r = 0; r < 4; ++r) {
                    const int co = mt * 16 + quad * 4 + r;
                    if (co < 81) {
                        const float v = acc[mt][nt][r] + bias[co];
                        fx += v * (float)(co % 9 - 4);
                        fy += v * (float)(co / 9 - 4);
                    }
                }
            fx += __shfl_xor(fx, 16, 64); fx += __shfl_xor(fx, 32, 64);
            fy += __shfl_xor(fy, 16, 64); fy += __shfl_xor(fy, 32, 64);
            const int px = x0 + nt * 16 + n16;
            if (quad == 0)      fout[(size_t)b * 2 * HWn + y * Ww + px]       = fx * (1.f / 81.f);
            else if (quad == 1) fout[((size_t)b * 2 + 1) * HWn + y * Ww + px] = fy * (1.f / 81.f);
        }
    }
}

// ---------------------------------------------------------------------------
// d_out = [flow: 4*2*HW] ++ [feat fp32: 4*433*HW].
// d_ws  = [bf16 shadow feat: 120.2 MB] ++ [bf16 weights: 2.2 MB].
// feat channel plan: [c5:0-31][c4:32-95][c3:96-159][c2:160-255][c1:256-351][vol:352-432]
// Each conv reads suffix [CS,448) of the shadow (pad channels are zero).
// ---------------------------------------------------------------------------
extern "C" void kernel_launch(void* const* d_in, const int* in_sizes, int n_in,
                              void* d_out, int out_size, void* d_ws, size_t ws_size,
                              hipStream_t stream)
{
    const float* tenFirst  = (const float*)d_in[0];
    const float* tenSecond = (const float*)d_in[1];
    const float* W1 = (const float*)d_in[2];   const float* b1 = (const float*)d_in[3];
    const float* W2 = (const float*)d_in[4];   const float* b2 = (const float*)d_in[5];
    const float* W3 = (const float*)d_in[6];   const float* b3 = (const float*)d_in[7];
    const float* W4 = (const float*)d_in[8];   const float* b4 = (const float*)d_in[9];
    const float* W5 = (const float*)d_in[10];  const float* b5 = (const float*)d_in[11];
    const float* Wf = (const float*)d_in[12];  const float* bf = (const float*)d_in[13];

    float* out  = (float*)d_out;
    float* feat = out + FLOW_ELEMS;

    unsigned short* fbf   = (unsigned short*)d_ws;
    unsigned short* wbase = fbf + FEATBF_ELEMS;
    const size_t o1 = 0;
    const size_t o2 = o1 + (size_t)9 * 96 * 96;
    const size_t o3 = o2 + (size_t)9 * 96 * 192;
    const size_t o4 = o3 + (size_t)9 * 64 * 288;
    const size_t o5 = o4 + (size_t)9 * 64 * 352;
    const size_t of = o5 + (size_t)9 * 32 * 416;

    // zero shadow (halos + channel pad must be 0 every launch; ws is re-poisoned)
    hipMemsetAsync(d_ws, 0, FEATBF_ELEMS * sizeof(unsigned short), stream);

    auto wt = [&](const float* src, unsigned short* dst, int CO, int CI, int COP, int CIP) {
        int n = 9 * COP * CIP;
        wtrans<<<(n + 255) / 256, 256, 0, stream>>>(src, dst, CO, CI, COP, CIP);
    };
    wt(W1, wbase + o1, 96,  81, 96,  96);
    wt(W2, wbase + o2, 96, 177, 96, 192);
    wt(W3, wbase + o3, 64, 273, 64, 288);
    wt(W4, wbase + o4, 64, 337, 64, 352);
    wt(W5, wbase + o5, 32, 401, 32, 416);
    wt(Wf, wbase + of, 81, 433, 96, 448);

    corr_kernel<<<dim3(Hh, Bn), 256, 0, stream>>>(tenFirst, tenSecond, feat, fbf);

    conv_mfma< 96, 6, false><<<dim3(Hh, Bn), 256, 0, stream>>>(fbf, wbase + o1, b1, feat + (size_t)256 * HWn, fbf, 256);
    conv_mfma<192, 6, false><<<dim3(Hh, Bn), 256, 0, stream>>>(fbf, wbase + o2, b2, feat + (size_t)160 * HWn, fbf, 160);
    conv_mfma<288, 4, false><<<dim3(Hh, Bn), 256, 0, stream>>>(fbf, wbase + o3, b3, feat + (size_t) 96 * HWn, fbf,  96);
    conv_mfma<352, 4, false><<<dim3(Hh, Bn), 256, 0, stream>>>(fbf, wbase + o4, b4, feat + (size_t) 32 * HWn, fbf,  32);
    conv_mfma<416, 2, false><<<dim3(Hh, Bn), 256, 0, stream>>>(fbf, wbase + o5, b5, feat,                     fbf,   0);
    conv_mfma<448, 6, true ><<<dim3(Hh, Bn), 256, 0, stream>>>(fbf, wbase + of, bf, out,                  nullptr,   0);
}

// Round 2
// 1700.806 us; speedup vs baseline: 1.1000x; 1.0798x over previous
//
#include <hip/hip_runtime.h>

// (B,C,H,W) = (4,96,128,256), level-6 decoder.
constexpr int Bn = 4, Hh = 128, Ww = 256, HWn = Hh * Ww;   // 32768
constexpr int FC = 433;
constexpr int FLOW_ELEMS = Bn * 2 * HWn;                    // 262144
// bf16 channel-minor shadow feat: [B][Hp][Wp][Cp], halos + channel pad zeroed
constexpr int Hp = 130, Wp = 258, Cp = 448;
constexpr size_t FB_BATCH = (size_t)Hp * Wp * Cp;           // 15,025,920
constexpr size_t FEATBF_ELEMS = (size_t)Bn * FB_BATCH;      // 60,103,680 (x2B = 120.2 MB)

using short8 = __attribute__((ext_vector_type(8))) short;   // 8 x bf16 (4 VGPRs)
using f32x4  = __attribute__((ext_vector_type(4))) float;

__device__ __forceinline__ unsigned short f2bf(float v) {
    union { float f; unsigned u; } x; x.f = v;
    unsigned r = x.u + 0x7fff + ((x.u >> 16) & 1);          // RNE
    return (unsigned short)(r >> 16);
}

// ---------------------------------------------------------------------------
// Weight pretransform: OIHW fp32 [CO][CI][3][3] -> bf16 [9][COP][CIP], zero-pad.
// ---------------------------------------------------------------------------
__global__ void wtrans(const float* __restrict__ src, unsigned short* __restrict__ dst,
                       int CO, int CI, int COP, int CIP)
{
    int idx = blockIdx.x * 256 + threadIdx.x;
    int total = 9 * COP * CIP;
    if (idx >= total) return;
    int t  = idx / (COP * CIP);
    int r  = idx % (COP * CIP);
    int co = r / CIP;
    int ci = r % CIP;
    float v = (co < CO && ci < CI) ? src[((size_t)co * CI + ci) * 9 + t] : 0.f;
    dst[idx] = f2bf(v);
}

// ---------------------------------------------------------------------------
// Correlation (fp32, double-buffered LDS pipeline) + lrelu.
// Block = one (b, y) row, 256 px. Per 3-channel chunk: issue next chunk's
// global loads to regs -> compute current LDS buffer -> write regs to other
// buffer -> ONE barrier. HBM latency hides under the 243-FMA compute phase.
// Grid is 1D (512) with chunked XCD swizzle (64 consecutive rows per XCD).
// ---------------------------------------------------------------------------
__global__ __launch_bounds__(256) void corr_kernel(
    const float* __restrict__ A, const float* __restrict__ B2,
    float* __restrict__ feat, unsigned short* __restrict__ fbf)
{
    constexpr int NC = 3;                         // channels per chunk
    constexpr int NCHUNK = 96 / NC;               // 32
    __shared__ float sB[2][NC][9][264];           // 57,024 B -> 2 blocks/CU

    const int x = threadIdx.x;
    const int w = blockIdx.x;                     // physical wg id (512)
    const int L = (w & 7) * 64 + (w >> 3);        // chunked XCD swizzle, bijective
    const int y = L & 127, b = L >> 7;

    // zero x-halo cols of BOTH buffers once (never rewritten)
    if (x < 8) {
        const int col = (x < 4) ? x : (256 + x);
#pragma unroll
        for (int bb = 0; bb < 2; ++bb)
#pragma unroll
            for (int cl = 0; cl < NC; ++cl)
#pragma unroll
                for (int row = 0; row < 9; ++row)
                    sB[bb][cl][row][col] = 0.f;
    }

    float acc[81];
#pragma unroll
    for (int d = 0; d < 81; ++d) acc[d] = 0.f;

    const size_t cb = (size_t)b * 96;
    const float* ap = A  + cb * HWn + y * Ww + x;
    const float* bp = B2 + cb * HWn + x;

    float rB[NC][9], rA[NC], av[NC];

    // prologue: load + write chunk 0
#pragma unroll
    for (int cl = 0; cl < NC; ++cl) {
        const float* src = bp + (size_t)cl * HWn;
#pragma unroll
        for (int row = 0; row < 9; ++row) {
            const int yy = y + row - 4;
            rB[cl][row] = ((unsigned)yy < 128u) ? src[yy * Ww] : 0.f;
        }
        rA[cl] = ap[(size_t)cl * HWn];
    }
#pragma unroll
    for (int cl = 0; cl < NC; ++cl) {
        av[cl] = rA[cl];
#pragma unroll
        for (int row = 0; row < 9; ++row) sB[0][cl][row][4 + x] = rB[cl][row];
    }
    __syncthreads();

    for (int k = 0; k < NCHUNK; ++k) {
        const int cur = k & 1;
        // issue next chunk's loads (latency overlaps with compute below)
        if (k + 1 < NCHUNK) {
            const int c0 = (k + 1) * NC;
#pragma unroll
            for (int cl = 0; cl < NC; ++cl) {
                const float* src = bp + (size_t)(c0 + cl) * HWn;
#pragma unroll
                for (int row = 0; row < 9; ++row) {
                    const int yy = y + row - 4;
                    rB[cl][row] = ((unsigned)yy < 128u) ? src[yy * Ww] : 0.f;
                }
                rA[cl] = ap[(size_t)(c0 + cl) * HWn];
            }
        }
        // compute current buffer
#pragma unroll
        for (int cl = 0; cl < NC; ++cl)
#pragma unroll
            for (int dy = 0; dy < 9; ++dy)
#pragma unroll
                for (int dx = 0; dx < 9; ++dx)
                    acc[dy * 9 + dx] = fmaf(av[cl], sB[cur][cl][dy][x + dx],
                                            acc[dy * 9 + dx]);
        // write next buffer (other buffer: its readers finished before last sync)
        if (k + 1 < NCHUNK) {
#pragma unroll
            for (int cl = 0; cl < NC; ++cl) {
                av[cl] = rA[cl];
#pragma unroll
                for (int row = 0; row < 9; ++row)
                    sB[cur ^ 1][cl][row][4 + x] = rB[cl][row];
            }
        }
        __syncthreads();
    }

    float* op = feat + ((size_t)b * FC + 352) * HWn + y * Ww + x;
    unsigned short bv16[81];
#pragma unroll
    for (int d = 0; d < 81; ++d) {
        float v = acc[d];
        v = (v >= 0.f) ? v : 0.1f * v;
        op[(size_t)d * HWn] = v;
        bv16[d] = f2bf(v);
    }
    unsigned short* bq = fbf + ((size_t)(b * Hp + y + 1) * Wp + (x + 1)) * Cp + 352;
#pragma unroll
    for (int k = 0; k < 20; ++k) {
        ushort4 p; p.x = bv16[4*k]; p.y = bv16[4*k+1]; p.z = bv16[4*k+2]; p.w = bv16[4*k+3];
        *(ushort4*)(bq + 4 * k) = p;
    }
    bq[80] = bv16[80];
}

// ---------------------------------------------------------------------------
// MFMA implicit-GEMM 3x3 conv. M=co (weights=A operand), N=pixels (input=B),
// K=ci. Wave = 32 px x (NT*16) co (NTP=2 pixel tiles -> 4096 waves = 16/CU).
// Grid: 1D 1024 blocks = (xh in 0..1, y, b), chunked XCD swizzle so 128
// consecutive (b,y,xh) blocks are co-resident on one XCD -> tap rows y+-1
// are L2-local. Reads channel suffix [CS,448) of the bf16 shadow.
// D: col(pixel)=l&15, row(co)=quad*4+r  [guide §3, m89/m120 verified].
// FUSE: flow head epilogue (bias + vx/vy weighted mean), no feat write.
// ---------------------------------------------------------------------------
template<int CIP, int NT, bool FUSE>
__global__ __launch_bounds__(256) void conv_mfma(
    const unsigned short* __restrict__ fbf,
    const unsigned short* __restrict__ Wt,     // [9][NT*16][CIP] bf16
    const float* __restrict__ bias,
    float* __restrict__ fout,                  // convs: feat + co_start*HW; flow: flow base
    unsigned short* __restrict__ bfout, int co_start)
{
    constexpr int CS  = 448 - CIP;
    constexpr int NTP = 2;                     // pixel tiles per wave (32 px)
    const int tid  = threadIdx.x;
    const int lane = tid & 63;
    const int wv   = tid >> 6;
    const int n16  = lane & 15;
    const int quad = lane >> 4;

    const int w = blockIdx.x;                  // physical wg id (1024)
    const int L = (w & 7) * 128 + (w >> 3);    // chunked XCD swizzle, bijective
    const int b  = L >> 8;
    const int r  = L & 255;
    const int y  = r >> 1;
    const int xh = r & 1;
    const int x0 = xh * 128 + wv * 32;

    f32x4 acc[NT][NTP];
#pragma unroll
    for (int mt = 0; mt < NT; ++mt)
#pragma unroll
        for (int nt = 0; nt < NTP; ++nt)
#pragma unroll
            for (int rr = 0; rr < 4; ++rr) acc[mt][nt][rr] = 0.f;

    if (!FUSE) {
#pragma unroll
        for (int mt = 0; mt < NT; ++mt) {
            f32x4 bv = *(const f32x4*)(bias + mt * 16 + quad * 4);
#pragma unroll
            for (int nt = 0; nt < NTP; ++nt) acc[mt][nt] = bv;
        }
    }

    const unsigned short* fb = fbf + (size_t)b * FB_BATCH;
    const int xb = x0 + n16 + 1;   // padded-x for dx=0

#pragma unroll 1
    for (int ci0 = 0; ci0 < CIP; ci0 += 32) {
#pragma unroll
        for (int tap = 0; tap < 9; ++tap) {
            const int dy = tap / 3 - 1, dx = tap % 3 - 1;
            const unsigned short* bp =
                fb + ((size_t)(y + 1 + dy) * Wp + (xb + dx)) * Cp + (CS + ci0 + quad * 8);
            short8 Bf[NTP];
#pragma unroll
            for (int nt = 0; nt < NTP; ++nt)
                Bf[nt] = *(const short8*)(bp + (size_t)nt * 16 * Cp);

            const unsigned short* apw =
                Wt + ((size_t)tap * (NT * 16) + n16) * CIP + (ci0 + quad * 8);
#pragma unroll
            for (int mt = 0; mt < NT; ++mt) {
                short8 Af = *(const short8*)(apw + (size_t)mt * 16 * CIP);
#pragma unroll
                for (int nt = 0; nt < NTP; ++nt)
                    acc[mt][nt] = __builtin_amdgcn_mfma_f32_16x16x32_bf16(
                        Af, Bf[nt], acc[mt][nt], 0, 0, 0);
            }
        }
    }

    if (!FUSE) {
#pragma unroll
        for (int mt = 0; mt < NT; ++mt)
#pragma unroll
            for (int nt = 0; nt < NTP; ++nt) {
                const int px = x0 + nt * 16 + n16;
                float* op = fout + ((size_t)b * FC + mt * 16 + quad * 4) * HWn + y * Ww + px;
                unsigned short* bq = bfout +
                    ((size_t)(b * Hp + y + 1) * Wp + (px + 1)) * Cp + co_start + mt * 16 + quad * 4;
                ushort4 pk;
                float v0 = acc[mt][nt][0]; v0 = v0 >= 0.f ? v0 : 0.1f * v0; op[0]       = v0; pk.x = f2bf(v0);
                float v1 = acc[mt][nt][1]; v1 = v1 >= 0.f ? v1 : 0.1f * v1; op[HWn]     = v1; pk.y = f2bf(v1);
                float v2 = acc[mt][nt][2]; v2 = v2 >= 0.f ? v2 : 0.1f * v2; op[2 * HWn] = v2; pk.z = f2bf(v2);
                float v3 = acc[mt][nt][3]; v3 = v3 >= 0.f ? v3 : 0.1f * v3; op[3 * HWn] = v3; pk.w = f2bf(v3);
                *(ushort4*)bq = pk;
            }
    } else {
#pragma unroll
        for (int nt = 0; nt < NTP; ++nt) {
            float fx = 0.f, fy = 0.f;
#pragma unroll
            for (int mt = 0; mt < NT; ++mt)
#pragma unroll
                for (int rr = 0; rr < 4; ++rr) {
                    const int co = mt * 16 + quad * 4 + rr;
                    if (co < 81) {
                        const float v = acc[mt][nt][rr] + bias[co];
                        fx += v * (float)(co % 9 - 4);
                        fy += v * (float)(co / 9 - 4);
                    }
                }
            fx += __shfl_xor(fx, 16, 64); fx += __shfl_xor(fx, 32, 64);
            fy += __shfl_xor(fy, 16, 64); fy += __shfl_xor(fy, 32, 64);
            const int px = x0 + nt * 16 + n16;
            if (quad == 0)      fout[(size_t)b * 2 * HWn + y * Ww + px]       = fx * (1.f / 81.f);
            else if (quad == 1) fout[((size_t)b * 2 + 1) * HWn + y * Ww + px] = fy * (1.f / 81.f);
        }
    }
}

// ---------------------------------------------------------------------------
// d_out = [flow: 4*2*HW] ++ [feat fp32: 4*433*HW].
// d_ws  = [bf16 shadow feat: 120.2 MB] ++ [bf16 weights: 2.2 MB].
// feat channel plan: [c5:0-31][c4:32-95][c3:96-159][c2:160-255][c1:256-351][vol:352-432]
// Each conv reads suffix [CS,448) of the shadow (pad channels are zero).
// ---------------------------------------------------------------------------
extern "C" void kernel_launch(void* const* d_in, const int* in_sizes, int n_in,
                              void* d_out, int out_size, void* d_ws, size_t ws_size,
                              hipStream_t stream)
{
    const float* tenFirst  = (const float*)d_in[0];
    const float* tenSecond = (const float*)d_in[1];
    const float* W1 = (const float*)d_in[2];   const float* b1 = (const float*)d_in[3];
    const float* W2 = (const float*)d_in[4];   const float* b2 = (const float*)d_in[5];
    const float* W3 = (const float*)d_in[6];   const float* b3 = (const float*)d_in[7];
    const float* W4 = (const float*)d_in[8];   const float* b4 = (const float*)d_in[9];
    const float* W5 = (const float*)d_in[10];  const float* b5 = (const float*)d_in[11];
    const float* Wf = (const float*)d_in[12];  const float* bf = (const float*)d_in[13];

    float* out  = (float*)d_out;
    float* feat = out + FLOW_ELEMS;

    unsigned short* fbf   = (unsigned short*)d_ws;
    unsigned short* wbase = fbf + FEATBF_ELEMS;
    const size_t o1 = 0;
    const size_t o2 = o1 + (size_t)9 * 96 * 96;
    const size_t o3 = o2 + (size_t)9 * 96 * 192;
    const size_t o4 = o3 + (size_t)9 * 64 * 288;
    const size_t o5 = o4 + (size_t)9 * 64 * 352;
    const size_t of = o5 + (size_t)9 * 32 * 416;

    // zero shadow (halos + channel pad must be 0 every launch; ws is re-poisoned)
    hipMemsetAsync(d_ws, 0, FEATBF_ELEMS * sizeof(unsigned short), stream);

    auto wt = [&](const float* src, unsigned short* dst, int CO, int CI, int COP, int CIP) {
        int n = 9 * COP * CIP;
        wtrans<<<(n + 255) / 256, 256, 0, stream>>>(src, dst, CO, CI, COP, CIP);
    };
    wt(W1, wbase + o1, 96,  81, 96,  96);
    wt(W2, wbase + o2, 96, 177, 96, 192);
    wt(W3, wbase + o3, 64, 273, 64, 288);
    wt(W4, wbase + o4, 64, 337, 64, 352);
    wt(W5, wbase + o5, 32, 401, 32, 416);
    wt(Wf, wbase + of, 81, 433, 96, 448);

    corr_kernel<<<dim3(512), 256, 0, stream>>>(tenFirst, tenSecond, feat, fbf);

    conv_mfma< 96, 6, false><<<dim3(1024), 256, 0, stream>>>(fbf, wbase + o1, b1, feat + (size_t)256 * HWn, fbf, 256);
    conv_mfma<192, 6, false><<<dim3(1024), 256, 0, stream>>>(fbf, wbase + o2, b2, feat + (size_t)160 * HWn, fbf, 160);
    conv_mfma<288, 4, false><<<dim3(1024), 256, 0, stream>>>(fbf, wbase + o3, b3, feat + (size_t) 96 * HWn, fbf,  96);
    conv_mfma<352, 4, false><<<dim3(1024), 256, 0, stream>>>(fbf, wbase + o4, b4, feat + (size_t) 32 * HWn, fbf,  32);
    conv_mfma<416, 2, false><<<dim3(1024), 256, 0, stream>>>(fbf, wbase + o5, b5, feat,                     fbf,   0);
    conv_mfma<448, 6, true ><<<dim3(1024), 256, 0, stream>>>(fbf, wbase + of, bf, out,                  nullptr,   0);
}

// Round 3
// 1650.783 us; speedup vs baseline: 1.1333x; 1.0303x over previous
//
#include <hip/hip_runtime.h>

// (B,C,H,W) = (4,96,128,256), level-6 decoder.
constexpr int Bn = 4, Hh = 128, Ww = 256, HWn = Hh * Ww;   // 32768
constexpr int FC = 433;
constexpr int FLOW_ELEMS = Bn * 2 * HWn;                    // 262144
// bf16 channel-minor shadow feat: [B][Hp][Wp][Cp], halos + channel pad zeroed
constexpr int Hp = 130, Wp = 258, Cp = 448;
constexpr size_t FB_BATCH = (size_t)Hp * Wp * Cp;           // 15,025,920
constexpr size_t FEATBF_ELEMS = (size_t)Bn * FB_BATCH;      // 60,103,680 (x2B = 120.2 MB)

using short8 = __attribute__((ext_vector_type(8))) short;   // 8 x bf16 (4 VGPRs)
using f32x4  = __attribute__((ext_vector_type(4))) float;

__device__ __forceinline__ unsigned short f2bf(float v) {
    union { float f; unsigned u; } x; x.f = v;
    unsigned r = x.u + 0x7fff + ((x.u >> 16) & 1);          // RNE
    return (unsigned short)(r >> 16);
}

// ---------------------------------------------------------------------------
// Weight pretransform: OIHW fp32 [CO][CI][3][3] -> bf16 [9][COP][CIP], zero-pad.
// ---------------------------------------------------------------------------
__global__ void wtrans(const float* __restrict__ src, unsigned short* __restrict__ dst,
                       int CO, int CI, int COP, int CIP)
{
    int idx = blockIdx.x * 256 + threadIdx.x;
    int total = 9 * COP * CIP;
    if (idx >= total) return;
    int t  = idx / (COP * CIP);
    int r  = idx % (COP * CIP);
    int co = r / CIP;
    int ci = r % CIP;
    float v = (co < CO && ci < CI) ? src[((size_t)co * CI + ci) * 9 + t] : 0.f;
    dst[idx] = f2bf(v);
}

// ---------------------------------------------------------------------------
// Correlation (fp32, double-buffered LDS pipeline) + lrelu.  (unchanged)
// ---------------------------------------------------------------------------
__global__ __launch_bounds__(256) void corr_kernel(
    const float* __restrict__ A, const float* __restrict__ B2,
    float* __restrict__ feat, unsigned short* __restrict__ fbf)
{
    constexpr int NC = 3;                         // channels per chunk
    constexpr int NCHUNK = 96 / NC;               // 32
    __shared__ float sB[2][NC][9][264];           // 57,024 B -> 2 blocks/CU

    const int x = threadIdx.x;
    const int w = blockIdx.x;                     // physical wg id (512)
    const int L = (w & 7) * 64 + (w >> 3);        // chunked XCD swizzle, bijective
    const int y = L & 127, b = L >> 7;

    if (x < 8) {
        const int col = (x < 4) ? x : (256 + x);
#pragma unroll
        for (int bb = 0; bb < 2; ++bb)
#pragma unroll
            for (int cl = 0; cl < NC; ++cl)
#pragma unroll
                for (int row = 0; row < 9; ++row)
                    sB[bb][cl][row][col] = 0.f;
    }

    float acc[81];
#pragma unroll
    for (int d = 0; d < 81; ++d) acc[d] = 0.f;

    const size_t cb = (size_t)b * 96;
    const float* ap = A  + cb * HWn + y * Ww + x;
    const float* bp = B2 + cb * HWn + x;

    float rB[NC][9], rA[NC], av[NC];

#pragma unroll
    for (int cl = 0; cl < NC; ++cl) {
        const float* src = bp + (size_t)cl * HWn;
#pragma unroll
        for (int row = 0; row < 9; ++row) {
            const int yy = y + row - 4;
            rB[cl][row] = ((unsigned)yy < 128u) ? src[yy * Ww] : 0.f;
        }
        rA[cl] = ap[(size_t)cl * HWn];
    }
#pragma unroll
    for (int cl = 0; cl < NC; ++cl) {
        av[cl] = rA[cl];
#pragma unroll
        for (int row = 0; row < 9; ++row) sB[0][cl][row][4 + x] = rB[cl][row];
    }
    __syncthreads();

    for (int k = 0; k < NCHUNK; ++k) {
        const int cur = k & 1;
        if (k + 1 < NCHUNK) {
            const int c0 = (k + 1) * NC;
#pragma unroll
            for (int cl = 0; cl < NC; ++cl) {
                const float* src = bp + (size_t)(c0 + cl) * HWn;
#pragma unroll
                for (int row = 0; row < 9; ++row) {
                    const int yy = y + row - 4;
                    rB[cl][row] = ((unsigned)yy < 128u) ? src[yy * Ww] : 0.f;
                }
                rA[cl] = ap[(size_t)(c0 + cl) * HWn];
            }
        }
#pragma unroll
        for (int cl = 0; cl < NC; ++cl)
#pragma unroll
            for (int dy = 0; dy < 9; ++dy)
#pragma unroll
                for (int dx = 0; dx < 9; ++dx)
                    acc[dy * 9 + dx] = fmaf(av[cl], sB[cur][cl][dy][x + dx],
                                            acc[dy * 9 + dx]);
        if (k + 1 < NCHUNK) {
#pragma unroll
            for (int cl = 0; cl < NC; ++cl) {
                av[cl] = rA[cl];
#pragma unroll
                for (int row = 0; row < 9; ++row)
                    sB[cur ^ 1][cl][row][4 + x] = rB[cl][row];
            }
        }
        __syncthreads();
    }

    float* op = feat + ((size_t)b * FC + 352) * HWn + y * Ww + x;
    unsigned short bv16[81];
#pragma unroll
    for (int d = 0; d < 81; ++d) {
        float v = acc[d];
        v = (v >= 0.f) ? v : 0.1f * v;
        op[(size_t)d * HWn] = v;
        bv16[d] = f2bf(v);
    }
    unsigned short* bq = fbf + ((size_t)(b * Hp + y + 1) * Wp + (x + 1)) * Cp + 352;
#pragma unroll
    for (int k = 0; k < 20; ++k) {
        ushort4 p; p.x = bv16[4*k]; p.y = bv16[4*k+1]; p.z = bv16[4*k+2]; p.w = bv16[4*k+3];
        *(ushort4*)(bq + 4 * k) = p;
    }
    bq[80] = bv16[80];
}

// ---------------------------------------------------------------------------
// MFMA implicit-GEMM 3x3 conv, LDS-staged B-operand (T14 pipeline).
// Block = 4 waves = 128 px of one row y. Per 32-ci chunk: stage 3 rows x
// 130 px x 32 ch (24.75 KB, single buffer) via reg-staged loads issued one
// chunk AHEAD (latency hides under previous chunk's MFMA). The 9 taps read
// LDS (ds_read_b128, slot-XOR swizzled: slot = quad ^ (px&3), same XOR both
// sides) instead of 9x redundant L3 loads. A (weights, L2-hot) stays global.
// D: col(pixel)=l&15, row(co)=quad*4+r. FUSE: flow-head epilogue.
// ---------------------------------------------------------------------------
template<int CIP, int NT, int MINW, bool FUSE>
__global__ __launch_bounds__(256, MINW) void conv_mfma(
    const unsigned short* __restrict__ fbf,
    const unsigned short* __restrict__ Wt,     // [9][NT*16][CIP] bf16
    const float* __restrict__ bias,
    float* __restrict__ fout,
    unsigned short* __restrict__ bfout, int co_start)
{
    constexpr int CS  = 448 - CIP;
    constexpr int NTP = 2;                     // pixel tiles per wave (32 px)
    constexpr int NCH = CIP / 32;
    constexpr int NTASK = 3 * 130 * 4;         // 16B granules per chunk = 1560

    __shared__ __align__(16) unsigned char sB[3 * 132 * 64];   // 25,344 B

    const int tid  = threadIdx.x;
    const int lane = tid & 63;
    const int wv   = tid >> 6;
    const int n16  = lane & 15;
    const int quad = lane >> 4;

    const int w = blockIdx.x;                  // physical wg id (1024)
    const int L = (w & 7) * 128 + (w >> 3);    // chunked XCD swizzle, bijective
    const int b  = L >> 8;
    const int r  = L & 255;
    const int y  = r >> 1;
    const int xh = r & 1;
    const int x0 = xh * 128;                   // block px base
    const int xw = x0 + wv * 32;               // wave px base

    f32x4 acc[NT][NTP];
#pragma unroll
    for (int mt = 0; mt < NT; ++mt)
#pragma unroll
        for (int nt = 0; nt < NTP; ++nt)
#pragma unroll
            for (int rr = 0; rr < 4; ++rr) acc[mt][nt][rr] = 0.f;

    if (!FUSE) {
#pragma unroll
        for (int mt = 0; mt < NT; ++mt) {
            f32x4 bv = *(const f32x4*)(bias + mt * 16 + quad * 4);
#pragma unroll
            for (int nt = 0; nt < NTP; ++nt) acc[mt][nt] = bv;
        }
    }

    const unsigned short* fb = fbf + (size_t)b * FB_BATCH;

    // LDS read addresses: per (nt, dxi) byte addr (row term added per tap)
    int pqa[NTP][3];
#pragma unroll
    for (int nt = 0; nt < NTP; ++nt)
#pragma unroll
        for (int dxi = 0; dxi < 3; ++dxi) {
            const int p = wv * 32 + nt * 16 + n16 + dxi;   // px slot 0..129
            pqa[nt][dxi] = (p << 6) + ((quad ^ (p & 3)) << 4);
        }

    short8 g[7];                               // staged granules (1 chunk ahead)

    // task tau -> (row, px slot p, lds slot qs); global quad qg = qs ^ (p&3)
    auto stage_load = [&](int ci0) {
#pragma unroll
        for (int i = 0; i < 7; ++i) {
            const int tau = tid + i * 256;
            if (tau < NTASK) {
                const int row = tau / 520;
                const int rem = tau - row * 520;
                const int p   = rem >> 2, qs = rem & 3;
                const int qg  = qs ^ (p & 3);
                const unsigned short* src =
                    fb + ((size_t)(y + row) * Wp + (x0 + p)) * Cp + (CS + ci0 + qg * 8);
                g[i] = *(const short8*)src;
            }
        }
    };
    auto stage_write = [&]() {
#pragma unroll
        for (int i = 0; i < 7; ++i) {
            const int tau = tid + i * 256;
            if (tau < NTASK) {
                const int row = tau / 520;
                const int rem = tau - row * 520;
                const int p   = rem >> 2, qs = rem & 3;
                *(short8*)(sB + ((row * 132 + p) << 6) + (qs << 4)) = g[i];
            }
        }
    };

    stage_load(0);

#pragma unroll 1
    for (int k = 0; k < NCH; ++k) {
        const int ci0 = k * 32;
        __syncthreads();                       // (A) prev chunk's readers done
        stage_write();                         // g (chunk k) -> LDS
        __syncthreads();                       // (B) writes visible
        if (k + 1 < NCH) stage_load(ci0 + 32); // fly under this chunk's MFMAs

        const char* bb = (const char*)sB;
#pragma unroll
        for (int tap = 0; tap < 9; ++tap) {
            const int dyi = tap / 3, dxi = tap % 3;
            short8 Bf[NTP];
#pragma unroll
            for (int nt = 0; nt < NTP; ++nt)
                Bf[nt] = *(const short8*)(bb + pqa[nt][dxi] + dyi * (132 * 64));

            const unsigned short* apw =
                Wt + ((size_t)tap * (NT * 16) + n16) * CIP + (ci0 + quad * 8);
#pragma unroll
            for (int mt = 0; mt < NT; ++mt) {
                short8 Af = *(const short8*)(apw + (size_t)mt * 16 * CIP);
#pragma unroll
                for (int nt = 0; nt < NTP; ++nt)
                    acc[mt][nt] = __builtin_amdgcn_mfma_f32_16x16x32_bf16(
                        Af, Bf[nt], acc[mt][nt], 0, 0, 0);
            }
        }
    }

    if (!FUSE) {
#pragma unroll
        for (int mt = 0; mt < NT; ++mt)
#pragma unroll
            for (int nt = 0; nt < NTP; ++nt) {
                const int px = xw + nt * 16 + n16;
                float* op = fout + ((size_t)b * FC + mt * 16 + quad * 4) * HWn + y * Ww + px;
                unsigned short* bq = bfout +
                    ((size_t)(b * Hp + y + 1) * Wp + (px + 1)) * Cp + co_start + mt * 16 + quad * 4;
                ushort4 pk;
                float v0 = acc[mt][nt][0]; v0 = v0 >= 0.f ? v0 : 0.1f * v0; op[0]       = v0; pk.x = f2bf(v0);
                float v1 = acc[mt][nt][1]; v1 = v1 >= 0.f ? v1 : 0.1f * v1; op[HWn]     = v1; pk.y = f2bf(v1);
                float v2 = acc[mt][nt][2]; v2 = v2 >= 0.f ? v2 : 0.1f * v2; op[2 * HWn] = v2; pk.z = f2bf(v2);
                float v3 = acc[mt][nt][3]; v3 = v3 >= 0.f ? v3 : 0.1f * v3; op[3 * HWn] = v3; pk.w = f2bf(v3);
                *(ushort4*)bq = pk;
            }
    } else {
#pragma unroll
        for (int nt = 0; nt < NTP; ++nt) {
            float fx = 0.f, fy = 0.f;
#pragma unroll
            for (int mt = 0; mt < NT; ++mt)
#pragma unroll
                for (int rr = 0; rr < 4; ++rr) {
                    const int co = mt * 16 + quad * 4 + rr;
                    if (co < 81) {
                        const float v = acc[mt][nt][rr] + bias[co];
                        fx += v * (float)(co % 9 - 4);
                        fy += v * (float)(co / 9 - 4);
                    }
                }
            fx += __shfl_xor(fx, 16, 64); fx += __shfl_xor(fx, 32, 64);
            fy += __shfl_xor(fy, 16, 64); fy += __shfl_xor(fy, 32, 64);
            const int px = xw + nt * 16 + n16;
            if (quad == 0)      fout[(size_t)b * 2 * HWn + y * Ww + px]       = fx * (1.f / 81.f);
            else if (quad == 1) fout[((size_t)b * 2 + 1) * HWn + y * Ww + px] = fy * (1.f / 81.f);
        }
    }
}

// ---------------------------------------------------------------------------
// d_out = [flow: 4*2*HW] ++ [feat fp32: 4*433*HW].
// d_ws  = [bf16 shadow feat: 120.2 MB] ++ [bf16 weights: 2.2 MB].
// feat channel plan: [c5:0-31][c4:32-95][c3:96-159][c2:160-255][c1:256-351][vol:352-432]
// ---------------------------------------------------------------------------
extern "C" void kernel_launch(void* const* d_in, const int* in_sizes, int n_in,
                              void* d_out, int out_size, void* d_ws, size_t ws_size,
                              hipStream_t stream)
{
    const float* tenFirst  = (const float*)d_in[0];
    const float* tenSecond = (const float*)d_in[1];
    const float* W1 = (const float*)d_in[2];   const float* b1 = (const float*)d_in[3];
    const float* W2 = (const float*)d_in[4];   const float* b2 = (const float*)d_in[5];
    const float* W3 = (const float*)d_in[6];   const float* b3 = (const float*)d_in[7];
    const float* W4 = (const float*)d_in[8];   const float* b4 = (const float*)d_in[9];
    const float* W5 = (const float*)d_in[10];  const float* b5 = (const float*)d_in[11];
    const float* Wf = (const float*)d_in[12];  const float* bf = (const float*)d_in[13];

    float* out  = (float*)d_out;
    float* feat = out + FLOW_ELEMS;

    unsigned short* fbf   = (unsigned short*)d_ws;
    unsigned short* wbase = fbf + FEATBF_ELEMS;
    const size_t o1 = 0;
    const size_t o2 = o1 + (size_t)9 * 96 * 96;
    const size_t o3 = o2 + (size_t)9 * 96 * 192;
    const size_t o4 = o3 + (size_t)9 * 64 * 288;
    const size_t o5 = o4 + (size_t)9 * 64 * 352;
    const size_t of = o5 + (size_t)9 * 32 * 416;

    // zero shadow (halos + channel pad must be 0 every launch; ws is re-poisoned)
    hipMemsetAsync(d_ws, 0, FEATBF_ELEMS * sizeof(unsigned short), stream);

    auto wt = [&](const float* src, unsigned short* dst, int CO, int CI, int COP, int CIP) {
        int n = 9 * COP * CIP;
        wtrans<<<(n + 255) / 256, 256, 0, stream>>>(src, dst, CO, CI, COP, CIP);
    };
    wt(W1, wbase + o1, 96,  81, 96,  96);
    wt(W2, wbase + o2, 96, 177, 96, 192);
    wt(W3, wbase + o3, 64, 273, 64, 288);
    wt(W4, wbase + o4, 64, 337, 64, 352);
    wt(W5, wbase + o5, 32, 401, 32, 416);
    wt(Wf, wbase + of, 81, 433, 96, 448);

    corr_kernel<<<dim3(512), 256, 0, stream>>>(tenFirst, tenSecond, feat, fbf);

    conv_mfma< 96, 6, 3, false><<<dim3(1024), 256, 0, stream>>>(fbf, wbase + o1, b1, feat + (size_t)256 * HWn, fbf, 256);
    conv_mfma<192, 6, 3, false><<<dim3(1024), 256, 0, stream>>>(fbf, wbase + o2, b2, feat + (size_t)160 * HWn, fbf, 160);
    conv_mfma<288, 4, 4, false><<<dim3(1024), 256, 0, stream>>>(fbf, wbase + o3, b3, feat + (size_t) 96 * HWn, fbf,  96);
    conv_mfma<352, 4, 4, false><<<dim3(1024), 256, 0, stream>>>(fbf, wbase + o4, b4, feat + (size_t) 32 * HWn, fbf,  32);
    conv_mfma<416, 2, 4, false><<<dim3(1024), 256, 0, stream>>>(fbf, wbase + o5, b5, feat,                     fbf,   0);
    conv_mfma<448, 6, 3, true ><<<dim3(1024), 256, 0, stream>>>(fbf, wbase + of, bf, out,                  nullptr,   0);
}

// Round 5
// 754.390 us; speedup vs baseline: 2.4799x; 2.1882x over previous
//
#include <hip/hip_runtime.h>

// (B,C,H,W) = (4,96,128,256), level-6 decoder.
constexpr int Bn = 4, Hh = 128, Ww = 256, HWn = Hh * Ww;   // 32768
constexpr int FC = 433;
constexpr int FLOW_ELEMS = Bn * 2 * HWn;                    // 262144
// bf16 channel-minor shadow feat: [B][Hp][Wp][Cp], halos + channel pad zeroed
constexpr int Hp = 130, Wp = 258, Cp = 448;
constexpr size_t FB_BATCH = (size_t)Hp * Wp * Cp;           // 15,025,920
constexpr size_t FEATBF_ELEMS = (size_t)Bn * FB_BATCH;      // 60,103,680 (x2B = 120.2 MB)

using short8 = __attribute__((ext_vector_type(8))) short;   // 8 x bf16 (4 VGPRs)
using f32x4  = __attribute__((ext_vector_type(4))) float;

__device__ __forceinline__ unsigned short f2bf(float v) {
    union { float f; unsigned u; } x; x.f = v;
    unsigned r = x.u + 0x7fff + ((x.u >> 16) & 1);          // RNE
    return (unsigned short)(r >> 16);
}

// ---------------------------------------------------------------------------
// Weight pretransform: OIHW fp32 [CO][CI][3][3] -> bf16 [9][COP][CIP], zero-pad.
// ---------------------------------------------------------------------------
__global__ void wtrans(const float* __restrict__ src, unsigned short* __restrict__ dst,
                       int CO, int CI, int COP, int CIP)
{
    int idx = blockIdx.x * 256 + threadIdx.x;
    int total = 9 * COP * CIP;
    if (idx >= total) return;
    int t  = idx / (COP * CIP);
    int r  = idx % (COP * CIP);
    int co = r / CIP;
    int ci = r % CIP;
    float v = (co < CO && ci < CI) ? src[((size_t)co * CI + ci) * 9 + t] : 0.f;
    dst[idx] = f2bf(v);
}

// ---------------------------------------------------------------------------
// Correlation (fp32, double-buffered LDS pipeline) + lrelu.  (unchanged)
// ---------------------------------------------------------------------------
__global__ __launch_bounds__(256) void corr_kernel(
    const float* __restrict__ A, const float* __restrict__ B2,
    float* __restrict__ feat, unsigned short* __restrict__ fbf)
{
    constexpr int NC = 3;
    constexpr int NCHUNK = 96 / NC;
    __shared__ float sB[2][NC][9][264];

    const int x = threadIdx.x;
    const int w = blockIdx.x;
    const int L = (w & 7) * 64 + (w >> 3);
    const int y = L & 127, b = L >> 7;

    if (x < 8) {
        const int col = (x < 4) ? x : (256 + x);
#pragma unroll
        for (int bb = 0; bb < 2; ++bb)
#pragma unroll
            for (int cl = 0; cl < NC; ++cl)
#pragma unroll
                for (int row = 0; row < 9; ++row)
                    sB[bb][cl][row][col] = 0.f;
    }

    float acc[81];
#pragma unroll
    for (int d = 0; d < 81; ++d) acc[d] = 0.f;

    const size_t cb = (size_t)b * 96;
    const float* ap = A  + cb * HWn + y * Ww + x;
    const float* bp = B2 + cb * HWn + x;

    float rB[NC][9], rA[NC], av[NC];

#pragma unroll
    for (int cl = 0; cl < NC; ++cl) {
        const float* src = bp + (size_t)cl * HWn;
#pragma unroll
        for (int row = 0; row < 9; ++row) {
            const int yy = y + row - 4;
            rB[cl][row] = ((unsigned)yy < 128u) ? src[yy * Ww] : 0.f;
        }
        rA[cl] = ap[(size_t)cl * HWn];
    }
#pragma unroll
    for (int cl = 0; cl < NC; ++cl) {
        av[cl] = rA[cl];
#pragma unroll
        for (int row = 0; row < 9; ++row) sB[0][cl][row][4 + x] = rB[cl][row];
    }
    __syncthreads();

    for (int k = 0; k < NCHUNK; ++k) {
        const int cur = k & 1;
        if (k + 1 < NCHUNK) {
            const int c0 = (k + 1) * NC;
#pragma unroll
            for (int cl = 0; cl < NC; ++cl) {
                const float* src = bp + (size_t)(c0 + cl) * HWn;
#pragma unroll
                for (int row = 0; row < 9; ++row) {
                    const int yy = y + row - 4;
                    rB[cl][row] = ((unsigned)yy < 128u) ? src[yy * Ww] : 0.f;
                }
                rA[cl] = ap[(size_t)(c0 + cl) * HWn];
            }
        }
#pragma unroll
        for (int cl = 0; cl < NC; ++cl)
#pragma unroll
            for (int dy = 0; dy < 9; ++dy)
#pragma unroll
                for (int dx = 0; dx < 9; ++dx)
                    acc[dy * 9 + dx] = fmaf(av[cl], sB[cur][cl][dy][x + dx],
                                            acc[dy * 9 + dx]);
        if (k + 1 < NCHUNK) {
#pragma unroll
            for (int cl = 0; cl < NC; ++cl) {
                av[cl] = rA[cl];
#pragma unroll
                for (int row = 0; row < 9; ++row)
                    sB[cur ^ 1][cl][row][4 + x] = rB[cl][row];
            }
        }
        __syncthreads();
    }

    float* op = feat + ((size_t)b * FC + 352) * HWn + y * Ww + x;
    unsigned short bv16[81];
#pragma unroll
    for (int d = 0; d < 81; ++d) {
        float v = acc[d];
        v = (v >= 0.f) ? v : 0.1f * v;
        op[(size_t)d * HWn] = v;
        bv16[d] = f2bf(v);
    }
    unsigned short* bq = fbf + ((size_t)(b * Hp + y + 1) * Wp + (x + 1)) * Cp + 352;
#pragma unroll
    for (int k = 0; k < 20; ++k) {
        ushort4 p; p.x = bv16[4*k]; p.y = bv16[4*k+1]; p.z = bv16[4*k+2]; p.w = bv16[4*k+3];
        *(ushort4*)(bq + 4 * k) = p;
    }
    bq[80] = bv16[80];
}

// ---------------------------------------------------------------------------
// MFMA implicit-GEMM 3x3 conv — MFMA phase is 100% LDS-fed (both A and B
// staged per 32-ci chunk; the ONLY global loads per chunk are the reg-staged
// prefetch for chunk k+1, issued after bar B and consumed after next bar A,
// so their latency hides under the full tap loop and in-order vmcnt waits
// never touch them mid-loop).
// Block = 2 output rows x 128 px. 4 waves: ry = wv>>1 (row), wc = wv&1
// (64px column). Wave = 64 px x NT*16 co (NTP=4 -> Af reused 4x).
// LDS: sB = 4 rows x 132 px x 4 granules x 16B = 33,792 B; sW = NT*9,216 B.
// All instantiations keep sB+sW <= 61,440 B (static-__shared__ 64 KiB limit;
// NT<=3). Granule-XOR swizzle (p>>1)&3 on both sides (B-row stride is 64 B
// -> bank-group period 2 px) -> conflict-free b128 reads.
// Multi-co-block convs (NCOB=2) split co range; adjacent L share B in L2.
// FUSE: flow head epilogue, partials merged via atomicAdd (flow pre-zeroed).
// ---------------------------------------------------------------------------
template<int CIP, int NT, int COTOT, int NCOB, bool FUSE>
__global__ __launch_bounds__(256, 2) void conv_mfma(
    const unsigned short* __restrict__ fbf,
    const unsigned short* __restrict__ Wt,     // [9][COTOT][CIP] bf16
    const float* __restrict__ bias,
    float* __restrict__ fout,
    unsigned short* __restrict__ bfout, int co_start)
{
    constexpr int CS  = 448 - CIP;
    constexpr int NCH = CIP / 32;
    constexpr int NTB = 4 * 132 * 4;           // 2112 B granules / chunk
    constexpr int NTW = 9 * NT * 16 * 4;       // W granules / chunk
    constexpr int IB  = (NTB + 255) / 256;     // 9
    constexpr int IW  = (NTW + 255) / 256;

    __shared__ __align__(16) unsigned char sB[4 * 132 * 64];      // 33,792 B
    __shared__ __align__(16) unsigned char sW[(size_t)NT * 9216]; // NT*9 KB

    const int tid  = threadIdx.x;
    const int lane = tid & 63;
    const int wv   = tid >> 6;
    const int n16  = lane & 15;
    const int quad = lane >> 4;
    const int ry   = wv >> 1;                  // output row within block
    const int wc   = wv & 1;                   // 64px column within 128px

    constexpr int NBLK = 512 * NCOB;
    const int w = blockIdx.x;
    const int L = (w & 7) * (NBLK / 8) + (w >> 3);   // chunked XCD swizzle
    const int cbk = (NCOB == 2) ? (L & 1) : 0;       // co-block (adjacent ->
    const int t   = (NCOB == 2) ? (L >> 1) : L;      //  shares B in L2)
    const int b   = t >> 7;
    const int rr_ = t & 127;
    const int y2  = rr_ >> 1;
    const int xh  = rr_ & 1;
    const int y0  = y2 * 2;                    // padded rows y0..y0+3
    const int xb0 = xh * 128;                  // padded px base
    const int cob = cbk * NT * 16;

    f32x4 acc[NT][4];
#pragma unroll
    for (int mt = 0; mt < NT; ++mt)
#pragma unroll
        for (int nt = 0; nt < 4; ++nt)
#pragma unroll
            for (int rr = 0; rr < 4; ++rr) acc[mt][nt][rr] = 0.f;

    if (!FUSE) {
#pragma unroll
        for (int mt = 0; mt < NT; ++mt) {
            f32x4 bv = *(const f32x4*)(bias + cob + mt * 16 + quad * 4);
#pragma unroll
            for (int nt = 0; nt < 4; ++nt) acc[mt][nt] = bv;
        }
    }

    const unsigned short* fb = fbf + (size_t)b * FB_BATCH;

    // LDS read addresses
    int pqa[4][3];
#pragma unroll
    for (int nt = 0; nt < 4; ++nt)
#pragma unroll
        for (int dxi = 0; dxi < 3; ++dxi) {
            const int p = wc * 64 + nt * 16 + n16 + dxi;      // 0..129
            pqa[nt][dxi] = p * 64 + ((quad ^ ((p >> 1) & 3)) << 4);
        }
    const int rowoff = ry * (132 * 64);
    const int wqa = n16 * 64 + ((quad ^ ((n16 >> 1) & 3)) << 4);

    short8 gB[IB], gW[IW];

    auto stage_load = [&](int ci0) {
#pragma unroll
        for (int i = 0; i < IB; ++i) {
            const int tau = tid + i * 256;
            if (tau < NTB) {
                const int row = tau / 528;
                const int rem = tau - row * 528;
                int p = rem >> 2; const int qs = rem & 3;
                if (p > 129) p = 129;                          // pad clamp
                const int qg = qs ^ ((p >> 1) & 3);
                gB[i] = *(const short8*)(fb +
                    ((size_t)(y0 + row) * Wp + (xb0 + p)) * Cp + (CS + ci0 + qg * 8));
            }
        }
#pragma unroll
        for (int i = 0; i < IW; ++i) {
            const int tau = tid + i * 256;
            if (tau < NTW) {
                const int idx = tau >> 2, qs = tau & 3;
                const int n   = idx & 15;
                const int tm  = idx >> 4;
                const int tap = tm / NT, mt = tm - tap * NT;
                const int qg  = qs ^ ((n >> 1) & 3);
                gW[i] = *(const short8*)(Wt +
                    ((size_t)tap * COTOT + cob + mt * 16 + n) * CIP + (ci0 + qg * 8));
            }
        }
    };
    auto stage_write = [&]() {
#pragma unroll
        for (int i = 0; i < IB; ++i) {
            const int tau = tid + i * 256;
            if (tau < NTB) *(short8*)(sB + (size_t)tau * 16) = gB[i];
        }
#pragma unroll
        for (int i = 0; i < IW; ++i) {
            const int tau = tid + i * 256;
            if (tau < NTW) *(short8*)(sW + (size_t)tau * 16) = gW[i];
        }
    };

    stage_load(0);

#pragma unroll 1
    for (int k = 0; k < NCH; ++k) {
        __syncthreads();                        // A: prev readers done (+vm drain)
        stage_write();
        __syncthreads();                        // B: writes visible
        if (k + 1 < NCH) stage_load((k + 1) * 32);   // flies under tap loop

#pragma unroll
        for (int tap = 0; tap < 9; ++tap) {
            const int dyi = tap / 3, dxi = tap % 3;
            const unsigned char* bb = sB + rowoff + dyi * (132 * 64);
            short8 Bf[4];
#pragma unroll
            for (int nt = 0; nt < 4; ++nt)
                Bf[nt] = *(const short8*)(bb + pqa[nt][dxi]);
            const unsigned char* wb = sW + tap * (NT * 1024) + wqa;
#pragma unroll
            for (int mt = 0; mt < NT; ++mt) {
                short8 Af = *(const short8*)(wb + mt * 1024);
#pragma unroll
                for (int nt = 0; nt < 4; ++nt)
                    acc[mt][nt] = __builtin_amdgcn_mfma_f32_16x16x32_bf16(
                        Af, Bf[nt], acc[mt][nt], 0, 0, 0);
            }
        }
    }

    const int yo = y0 + ry;
    if (!FUSE) {
#pragma unroll
        for (int mt = 0; mt < NT; ++mt)
#pragma unroll
            for (int nt = 0; nt < 4; ++nt) {
                const int px = xh * 128 + wc * 64 + nt * 16 + n16;
                const int coL = cob + mt * 16 + quad * 4;
                float* op = fout + ((size_t)b * FC + coL) * HWn + yo * Ww + px;
                unsigned short* bq = bfout +
                    ((size_t)(b * Hp + yo + 1) * Wp + (px + 1)) * Cp + co_start + coL;
                ushort4 pk;
                float v0 = acc[mt][nt][0]; v0 = v0 >= 0.f ? v0 : 0.1f * v0; op[0]       = v0; pk.x = f2bf(v0);
                float v1 = acc[mt][nt][1]; v1 = v1 >= 0.f ? v1 : 0.1f * v1; op[HWn]     = v1; pk.y = f2bf(v1);
                float v2 = acc[mt][nt][2]; v2 = v2 >= 0.f ? v2 : 0.1f * v2; op[2 * HWn] = v2; pk.z = f2bf(v2);
                float v3 = acc[mt][nt][3]; v3 = v3 >= 0.f ? v3 : 0.1f * v3; op[3 * HWn] = v3; pk.w = f2bf(v3);
                *(ushort4*)bq = pk;
            }
    } else {
#pragma unroll
        for (int nt = 0; nt < 4; ++nt) {
            float fx = 0.f, fy = 0.f;
#pragma unroll
            for (int mt = 0; mt < NT; ++mt)
#pragma unroll
                for (int rr = 0; rr < 4; ++rr) {
                    const int co = cob + mt * 16 + quad * 4 + rr;
                    if (co < 81) {
                        const float v = acc[mt][nt][rr] + bias[co];
                        fx += v * (float)(co % 9 - 4);
                        fy += v * (float)(co / 9 - 4);
                    }
                }
            fx += __shfl_xor(fx, 16, 64); fx += __shfl_xor(fx, 32, 64);
            fy += __shfl_xor(fy, 16, 64); fy += __shfl_xor(fy, 32, 64);
            const int px = xh * 128 + wc * 64 + nt * 16 + n16;
            if (quad == 0)
                atomicAdd(&fout[(size_t)b * 2 * HWn + yo * Ww + px], fx * (1.f / 81.f));
            else if (quad == 1)
                atomicAdd(&fout[((size_t)b * 2 + 1) * HWn + yo * Ww + px], fy * (1.f / 81.f));
        }
    }
}

// ---------------------------------------------------------------------------
// d_out = [flow: 4*2*HW] ++ [feat fp32: 4*433*HW].
// d_ws  = [bf16 shadow feat: 120.2 MB] ++ [bf16 weights: 2.2 MB].
// feat channel plan: [c5:0-31][c4:32-95][c3:96-159][c2:160-255][c1:256-351][vol:352-432]
// ---------------------------------------------------------------------------
extern "C" void kernel_launch(void* const* d_in, const int* in_sizes, int n_in,
                              void* d_out, int out_size, void* d_ws, size_t ws_size,
                              hipStream_t stream)
{
    const float* tenFirst  = (const float*)d_in[0];
    const float* tenSecond = (const float*)d_in[1];
    const float* W1 = (const float*)d_in[2];   const float* b1 = (const float*)d_in[3];
    const float* W2 = (const float*)d_in[4];   const float* b2 = (const float*)d_in[5];
    const float* W3 = (const float*)d_in[6];   const float* b3 = (const float*)d_in[7];
    const float* W4 = (const float*)d_in[8];   const float* b4 = (const float*)d_in[9];
    const float* W5 = (const float*)d_in[10];  const float* b5 = (const float*)d_in[11];
    const float* Wf = (const float*)d_in[12];  const float* bf = (const float*)d_in[13];

    float* out  = (float*)d_out;
    float* feat = out + FLOW_ELEMS;

    unsigned short* fbf   = (unsigned short*)d_ws;
    unsigned short* wbase = fbf + FEATBF_ELEMS;
    const size_t o1 = 0;
    const size_t o2 = o1 + (size_t)9 * 96 * 96;
    const size_t o3 = o2 + (size_t)9 * 96 * 192;
    const size_t o4 = o3 + (size_t)9 * 64 * 288;
    const size_t o5 = o4 + (size_t)9 * 64 * 352;
    const size_t of = o5 + (size_t)9 * 32 * 416;

    // zero shadow (halos + channel pad) and the flow output (atomic merge target)
    hipMemsetAsync(d_ws, 0, FEATBF_ELEMS * sizeof(unsigned short), stream);
    hipMemsetAsync(out, 0, FLOW_ELEMS * sizeof(float), stream);

    auto wt = [&](const float* src, unsigned short* dst, int CO, int CI, int COP, int CIP) {
        int n = 9 * COP * CIP;
        wtrans<<<(n + 255) / 256, 256, 0, stream>>>(src, dst, CO, CI, COP, CIP);
    };
    wt(W1, wbase + o1, 96,  81, 96,  96);
    wt(W2, wbase + o2, 96, 177, 96, 192);
    wt(W3, wbase + o3, 64, 273, 64, 288);
    wt(W4, wbase + o4, 64, 337, 64, 352);
    wt(W5, wbase + o5, 32, 401, 32, 416);
    wt(Wf, wbase + of, 81, 433, 96, 448);

    corr_kernel<<<dim3(512), 256, 0, stream>>>(tenFirst, tenSecond, feat, fbf);

    conv_mfma< 96, 3, 96, 2, false><<<dim3(1024), 256, 0, stream>>>(fbf, wbase + o1, b1, feat + (size_t)256 * HWn, fbf, 256);
    conv_mfma<192, 3, 96, 2, false><<<dim3(1024), 256, 0, stream>>>(fbf, wbase + o2, b2, feat + (size_t)160 * HWn, fbf, 160);
    conv_mfma<288, 2, 64, 2, false><<<dim3(1024), 256, 0, stream>>>(fbf, wbase + o3, b3, feat + (size_t) 96 * HWn, fbf,  96);
    conv_mfma<352, 2, 64, 2, false><<<dim3(1024), 256, 0, stream>>>(fbf, wbase + o4, b4, feat + (size_t) 32 * HWn, fbf,  32);
    conv_mfma<416, 2, 32, 1, false><<<dim3( 512), 256, 0, stream>>>(fbf, wbase + o5, b5, feat,                     fbf,   0);
    conv_mfma<448, 3, 96, 2, true ><<<dim3(1024), 256, 0, stream>>>(fbf, wbase + of, bf, out,                  nullptr,   0);
}